// Round 1
// baseline (35.153 us; speedup 1.0000x reference)
//
#include <hip/hip_runtime.h>

constexpr int A_TOTAL = 5456;
constexpr int BATCH = 16;
constexpr int NUM_CLASSES = 80;
constexpr int NUM_CH = NUM_CLASSES + 2;   // 82
constexpr int MAX_OBJ = 32;
constexpr int LEVELS = 5;
constexpr int BINS = MAX_OBJ * LEVELS;    // 160

__device__ __forceinline__ int lev_of(int a) {
    return (a < 4096) ? 0 : (a < 5120) ? 1 : (a < 5376) ? 2 : (a < 5440) ? 3 : 4;
}

// Kernel A: per-anchor loss (focal + giou) + per-(b,o,l) sum/count histogram.
__global__ void loss_accum_kernel(const float* __restrict__ cls_pred,
                                  const float* __restrict__ loc_pred,
                                  const float* __restrict__ cls_tar,
                                  const float* __restrict__ loc_tar,
                                  const int*   __restrict__ ind_tar,
                                  float* __restrict__ g_sum,
                                  float* __restrict__ g_cnt) {
    __shared__ float s_sum[BINS];
    __shared__ float s_cnt[BINS];
    const int t = threadIdx.x;
    for (int i = t; i < BINS; i += blockDim.x) { s_sum[i] = 0.f; s_cnt[i] = 0.f; }
    __syncthreads();

    const int b = blockIdx.y;
    const int a = blockIdx.x * blockDim.x + t;
    if (a < A_TOTAL) {
        const size_t row = (size_t)b * A_TOTAL + a;
        // focal loss over 80 classes
        const float4* pred4 = (const float4*)(cls_pred + row * NUM_CLASSES); // 320B-aligned rows
        const float2* tar2  = (const float2*)(cls_tar  + row * NUM_CH);      // 8B-aligned rows
        float fl = 0.f;
        #pragma unroll 5
        for (int c = 0; c < NUM_CLASSES / 4; ++c) {
            float4 p4 = pred4[c];
            float2 ta = tar2[2 * c];
            float2 tb = tar2[2 * c + 1];
            float ps[4] = {p4.x, p4.y, p4.z, p4.w};
            float ts[4] = {ta.x, ta.y, tb.x, tb.y};
            #pragma unroll
            for (int j = 0; j < 4; ++j) {
                float p  = fminf(fmaxf(ps[j], 1e-7f), 1.0f - 1e-7f);
                float tt = ts[j];
                float ce = -(tt * __logf(p) + (1.f - tt) * __logf(1.f - p));
                float alpha_t = tt * 0.25f + (1.f - tt) * 0.75f;
                float pt = tt * (1.f - p) + (1.f - tt) * p;
                fl += alpha_t * pt * pt * ce;
            }
        }
        // giou loss (ltrb distance encoding)
        float4 T = ((const float4*)(loc_tar  + row * 4))[0];
        float4 P = ((const float4*)(loc_pred + row * 4))[0];
        float area_t = (T.x + T.z) * (T.y + T.w);
        float area_p = (P.x + P.z) * (P.y + P.w);
        float inter  = (fminf(T.x, P.x) + fminf(T.z, P.z)) * (fminf(T.y, P.y) + fminf(T.w, P.w));
        float uni    = area_t + area_p - inter;
        float iou    = inter / fmaxf(uni, 1e-7f);
        float enc    = (fmaxf(T.x, P.x) + fmaxf(T.z, P.z)) * (fmaxf(T.y, P.y) + fmaxf(T.w, P.w));
        float giou   = iou - (enc - uni) / fmaxf(enc, 1e-7f);
        float loss   = fl + (1.f - giou);

        int o = ind_tar[row];
        int l = lev_of(a);
        atomicAdd(&s_sum[o * LEVELS + l], loss);
        atomicAdd(&s_cnt[o * LEVELS + l], 1.0f);
    }
    __syncthreads();
    for (int i = t; i < BINS; i += blockDim.x) {
        float c = s_cnt[i];
        if (c != 0.f) {
            atomicAdd(&g_sum[b * BINS + i], s_sum[i]);
            atomicAdd(&g_cnt[b * BINS + i], c);
        }
    }
}

// Kernel B: per-(b,o) target computation (mean -> normalize -> top-3 -> valid mask)
__global__ void target_kernel(const float* __restrict__ g_sum,
                              const float* __restrict__ g_cnt,
                              const int*   __restrict__ bbox_cnt,
                              float* __restrict__ g_tgt) {
    int idx = blockIdx.x * blockDim.x + threadIdx.x;
    if (idx >= BATCH * MAX_OBJ) return;
    const int b = idx / MAX_OBJ;
    const int o = idx % MAX_OBJ;

    float mean[LEVELS];
    float mx = -1e30f;
    #pragma unroll
    for (int l = 0; l < LEVELS; ++l) {
        float s = g_sum[idx * LEVELS + l];
        float c = g_cnt[idx * LEVELS + l];
        mean[l] = s / fmaxf(1.0f, c);
        mx = fmaxf(mx, mean[l]);
    }
    float lmax = mx + 1e-5f;
    float mn = 1e30f;
    #pragma unroll
    for (int l = 0; l < LEVELS; ++l) {
        if (mean[l] == 0.0f) mean[l] = lmax;
        mn = fminf(mn, mean[l]);
    }
    float denom = lmax - mn;
    float tgt[LEVELS];
    float m1 = -1e30f, m2 = -1e30f, m3 = -1e30f;
    #pragma unroll
    for (int l = 0; l < LEVELS; ++l) {
        float v = 1.0f - (mean[l] - mn) / denom;
        tgt[l] = v;
        if (v > m1)      { m3 = m2; m2 = m1; m1 = v; }
        else if (v > m2) { m3 = m2; m2 = v; }
        else if (v > m3) { m3 = v; }
    }
    const bool valid = o < bbox_cnt[b];
    #pragma unroll
    for (int l = 0; l < LEVELS; ++l) {
        float v = tgt[l];
        v = (v >= m3) ? v : 0.0f;
        v = valid ? v : 0.0f;
        g_tgt[idx * LEVELS + l] = v;
    }
}

// Kernel C: gather target back to anchors + pos-mask, write both outputs.
__global__ void gather_kernel(const float* __restrict__ cls_tar,
                              const int*   __restrict__ ind_tar,
                              const float* __restrict__ g_tgt,
                              float* __restrict__ out) {
    __shared__ float s_tgt[BINS];
    const int b = blockIdx.y;
    for (int i = threadIdx.x; i < BINS; i += blockDim.x)
        s_tgt[i] = g_tgt[b * BINS + i];
    __syncthreads();
    const int a = blockIdx.x * blockDim.x + threadIdx.x;
    if (a >= A_TOTAL) return;
    const size_t row = (size_t)b * A_TOTAL + a;
    float pos = cls_tar[row * NUM_CH + (NUM_CH - 1)];
    int o = ind_tar[row];
    float v = (pos > 0.0f) ? s_tgt[o * LEVELS + lev_of(a)] : 1.0f;
    out[row] = v;                                // output 0: [B, A, 1]
    out[(size_t)BATCH * A_TOTAL + row] = pos;    // output 1: [B, A]
}

extern "C" void kernel_launch(void* const* d_in, const int* in_sizes, int n_in,
                              void* d_out, int out_size, void* d_ws, size_t ws_size,
                              hipStream_t stream) {
    const float* cls_pred = (const float*)d_in[0];
    const float* loc_pred = (const float*)d_in[1];
    const float* cls_tar  = (const float*)d_in[2];
    const float* loc_tar  = (const float*)d_in[3];
    const int*   ind_tar  = (const int*)d_in[4];
    const int*   bbox_cnt = (const int*)d_in[5];
    float* out = (float*)d_out;

    float* g_sum = (float*)d_ws;
    float* g_cnt = g_sum + BATCH * BINS;
    float* g_tgt = g_cnt + BATCH * BINS;

    hipMemsetAsync(d_ws, 0, 2 * BATCH * BINS * sizeof(float), stream);

    dim3 blk(256);
    dim3 gridA((A_TOTAL + 255) / 256, BATCH);
    loss_accum_kernel<<<gridA, blk, 0, stream>>>(cls_pred, loc_pred, cls_tar, loc_tar,
                                                 ind_tar, g_sum, g_cnt);
    target_kernel<<<(BATCH * MAX_OBJ + 255) / 256, blk, 0, stream>>>(g_sum, g_cnt,
                                                                     bbox_cnt, g_tgt);
    gather_kernel<<<gridA, blk, 0, stream>>>(cls_tar, ind_tar, g_tgt, out);
}

// Round 2
// 28.420 us; speedup vs baseline: 1.2369x; 1.2369x over previous
//
#include <hip/hip_runtime.h>

constexpr int A_TOTAL = 5456;
constexpr int BATCH = 16;
constexpr int NUM_CLASSES = 80;
constexpr int NUM_CH = NUM_CLASSES + 2;   // 82
constexpr int MAX_OBJ = 32;
constexpr int LEVELS = 5;
constexpr int BINS = MAX_OBJ * LEVELS;    // 160
constexpr int BLK = 256;
constexpr int NBLK = (A_TOTAL + BLK - 1) / BLK;  // 22 blocks per batch

__device__ __forceinline__ int lev_of(int a) {
    return (a < 4096) ? 0 : (a < 5120) ? 1 : (a < 5376) ? 2 : (a < 5440) ? 3 : 4;
}

// Kernel A: per-anchor loss (focal + giou) -> per-block partial histograms
// (written unconditionally: no zero-init, no global atomics). Also writes the
// pos-mask output (cls_tar channel 81) so the gather never touches cls_tar.
__global__ void __launch_bounds__(BLK)
loss_accum_kernel(const float* __restrict__ cls_pred,
                  const float* __restrict__ loc_pred,
                  const float* __restrict__ cls_tar,
                  const float* __restrict__ loc_tar,
                  const int*   __restrict__ ind_tar,
                  float* __restrict__ p_sum,   // [B][NBLK][BINS]
                  float* __restrict__ p_cnt,   // [B][NBLK][BINS]
                  float* __restrict__ out) {
    __shared__ float s_sum[BINS];
    __shared__ float s_cnt[BINS];
    const int t = threadIdx.x;
    for (int i = t; i < BINS; i += BLK) { s_sum[i] = 0.f; s_cnt[i] = 0.f; }
    __syncthreads();

    const int b = blockIdx.y;
    const int a = blockIdx.x * BLK + t;
    if (a < A_TOTAL) {
        const size_t row = (size_t)b * A_TOTAL + a;
        const float4* pred4 = (const float4*)(cls_pred + row * NUM_CLASSES); // 320B rows, 16B aligned
        const float2* tar2  = (const float2*)(cls_tar  + row * NUM_CH);      // 328B rows, 8B aligned
        float fl = 0.f;
        #pragma unroll 5
        for (int c = 0; c < NUM_CLASSES / 4; ++c) {
            float4 p4 = pred4[c];
            float2 ta = tar2[2 * c];
            float2 tb = tar2[2 * c + 1];
            float ps[4] = {p4.x, p4.y, p4.z, p4.w};
            float ts[4] = {ta.x, ta.y, tb.x, tb.y};
            #pragma unroll
            for (int j = 0; j < 4; ++j) {
                float p  = fminf(fmaxf(ps[j], 1e-7f), 1.0f - 1e-7f);
                float tt = ts[j];
                float ce = -(tt * __logf(p) + (1.f - tt) * __logf(1.f - p));
                float alpha_t = tt * 0.25f + (1.f - tt) * 0.75f;
                float pt = tt * (1.f - p) + (1.f - tt) * p;
                fl += alpha_t * pt * pt * ce;
            }
        }
        float pos = tar2[40].y;                   // channel 81
        out[(size_t)BATCH * A_TOTAL + row] = pos; // output 1: [B, A]

        float4 T = ((const float4*)(loc_tar  + row * 4))[0];
        float4 P = ((const float4*)(loc_pred + row * 4))[0];
        float area_t = (T.x + T.z) * (T.y + T.w);
        float area_p = (P.x + P.z) * (P.y + P.w);
        float inter  = (fminf(T.x, P.x) + fminf(T.z, P.z)) * (fminf(T.y, P.y) + fminf(T.w, P.w));
        float uni    = area_t + area_p - inter;
        float iou    = inter / fmaxf(uni, 1e-7f);
        float enc    = (fmaxf(T.x, P.x) + fmaxf(T.z, P.z)) * (fmaxf(T.y, P.y) + fmaxf(T.w, P.w));
        float giou   = iou - (enc - uni) / fmaxf(enc, 1e-7f);
        float loss   = fl + (1.f - giou);

        int o = ind_tar[row];
        atomicAdd(&s_sum[o * LEVELS + lev_of(a)], loss);
        atomicAdd(&s_cnt[o * LEVELS + lev_of(a)], 1.0f);
    }
    __syncthreads();
    const size_t slot = ((size_t)b * NBLK + blockIdx.x) * BINS;
    for (int i = t; i < BINS; i += BLK) {
        p_sum[slot + i] = s_sum[i];
        p_cnt[slot + i] = s_cnt[i];
    }
}

// Kernel C: reduce partials (redundantly per block, L2-hot) -> per-(o,l) target
// -> gather to anchors, using pos already staged in d_out by kernel A.
__global__ void __launch_bounds__(BLK)
gather_kernel(const float* __restrict__ p_sum,
              const float* __restrict__ p_cnt,
              const int*   __restrict__ ind_tar,
              const int*   __restrict__ bbox_cnt,
              float* __restrict__ out) {
    __shared__ float s_mean[BINS];
    __shared__ float s_tgt[BINS];
    const int t = threadIdx.x;
    const int b = blockIdx.y;

    // reduce 22 partial histograms for this batch
    if (t < BINS) {
        float s = 0.f, c = 0.f;
        const size_t base = (size_t)b * NBLK * BINS + t;
        #pragma unroll
        for (int k = 0; k < NBLK; ++k) {
            s += p_sum[base + (size_t)k * BINS];
            c += p_cnt[base + (size_t)k * BINS];
        }
        s_mean[t] = s / fmaxf(1.0f, c);
    }
    __syncthreads();

    // per-object target (threads 0..31)
    if (t < MAX_OBJ) {
        float mean[LEVELS];
        float mx = -1e30f;
        #pragma unroll
        for (int l = 0; l < LEVELS; ++l) {
            mean[l] = s_mean[t * LEVELS + l];
            mx = fmaxf(mx, mean[l]);
        }
        float lmax = mx + 1e-5f;
        float mn = 1e30f;
        #pragma unroll
        for (int l = 0; l < LEVELS; ++l) {
            if (mean[l] == 0.0f) mean[l] = lmax;
            mn = fminf(mn, mean[l]);
        }
        float denom = lmax - mn;
        float tgt[LEVELS];
        float m1 = -1e30f, m2 = -1e30f, m3 = -1e30f;
        #pragma unroll
        for (int l = 0; l < LEVELS; ++l) {
            float v = 1.0f - (mean[l] - mn) / denom;
            tgt[l] = v;
            if (v > m1)      { m3 = m2; m2 = m1; m1 = v; }
            else if (v > m2) { m3 = m2; m2 = v; }
            else if (v > m3) { m3 = v; }
        }
        const bool valid = t < bbox_cnt[b];
        #pragma unroll
        for (int l = 0; l < LEVELS; ++l) {
            float v = tgt[l];
            v = (v >= m3) ? v : 0.0f;
            s_tgt[t * LEVELS + l] = valid ? v : 0.0f;
        }
    }
    __syncthreads();

    const int a = blockIdx.x * BLK + t;
    if (a >= A_TOTAL) return;
    const size_t row = (size_t)b * A_TOTAL + a;
    float pos = out[(size_t)BATCH * A_TOTAL + row];  // staged by kernel A
    int o = ind_tar[row];
    out[row] = (pos > 0.0f) ? s_tgt[o * LEVELS + lev_of(a)] : 1.0f;
}

extern "C" void kernel_launch(void* const* d_in, const int* in_sizes, int n_in,
                              void* d_out, int out_size, void* d_ws, size_t ws_size,
                              hipStream_t stream) {
    const float* cls_pred = (const float*)d_in[0];
    const float* loc_pred = (const float*)d_in[1];
    const float* cls_tar  = (const float*)d_in[2];
    const float* loc_tar  = (const float*)d_in[3];
    const int*   ind_tar  = (const int*)d_in[4];
    const int*   bbox_cnt = (const int*)d_in[5];
    float* out = (float*)d_out;

    float* p_sum = (float*)d_ws;                       // [16][22][160]
    float* p_cnt = p_sum + (size_t)BATCH * NBLK * BINS;

    dim3 blk(BLK);
    dim3 grid(NBLK, BATCH);
    loss_accum_kernel<<<grid, blk, 0, stream>>>(cls_pred, loc_pred, cls_tar, loc_tar,
                                                ind_tar, p_sum, p_cnt, out);
    gather_kernel<<<grid, blk, 0, stream>>>(p_sum, p_cnt, ind_tar, bbox_cnt, out);
}